// Round 5
// baseline (168.015 us; speedup 1.0000x reference)
//
#include <hip/hip_runtime.h>
#include <math.h>

#define TPB 256

// Problem constants
constexpr int Bc = 16, Tc = 1536;
constexpr int T2c = 192;           // T / P1
constexpr float EPSc = 1e-5f;
constexpr float NSLOPE = 0.2f;
constexpr int MDI = 16;            // padded in-degree stride (bytes); byte15 = indeg
constexpr int MDO = 8;             // padded out-degree stride (bytes)
constexpr float L2E = 1.4426950408889634f;

typedef float vf2 __attribute__((ext_vector_type(2)));

// Workspace layout (float offsets)
constexpr int OW_WEFF = 0;         // [32 k][32 f2]
constexpr int OW_CHL  = 1024;      // [32]
constexpr int OW_CES  = 1056;      // ces[4] | ced[4]
constexpr int OW_WES  = 1064;      // [4 h][32 k]
constexpr int OW_WED  = 1192;      // [4 h][32 k]
constexpr int OW_A2C2 = 1320;      // a2[32] | c2[32] folded bn2 affine
constexpr int OW_WFT  = 1384;      // [32 f2][32 k]  transposed weff
constexpr int OW_GRAPH= 2408;      // 417 ints packed byte graph
constexpr int OW_P    = 2825;      // [B][192][32]

// Packed graph byte offsets (SELF-EDGES EXCLUDED from lists):
//   [0,1024)    in-lists  isrc[d*16+e], e<15 (pad 0); byte d*16+15 = indeg(no-self)
//   [1024,1088) indeg[d]  (no-self, clamped 15)
//   [1088,1600) out-lists outdst[v*8+j], exactly 4 entries (KNN), pads 0
//   [1600,1664) outdeg[v]
//   [1664] max in-degree (no-self)
constexpr int GB_INTS = 417;

// gat LDS layout (float offsets)
constexpr int L_XT  = 0;           // xT [40 c][68 v]; row 39 = ones; ROTATION-SWIZZLED
constexpr int L_WB  = 2720;        // [4 h][8 t][68 v]
constexpr int L_Y   = 4896;        // [4 h][8 t][41]
constexpr int L_GR  = 6208;        // 417 ints packed graph
constexpr int L_TOT = 6625;        // 26.5 KB

// XT swizzle: column granule rotated by row: g' = (g + row) & 15.
// Keeps float4 (granule) alignment; S-writes become ~2-way (free),
// A-reads stay 2-way, C-reads granule-remapped.
__device__ __forceinline__ int xt_idx(int row, int g, int lo)
{
    return L_XT + row * 68 + (((g + row) & 15) << 2) + lo;
}

__device__ __forceinline__ vf2 shfl64v(vf2 xv, int src)
{
    return __builtin_bit_cast(vf2,
        (unsigned long long)__shfl(__builtin_bit_cast(unsigned long long, xv), src));
}

// exp2(leaky(ev)) with logits pre-scaled by log2(e)
__device__ __forceinline__ vf2 lexp2v(vf2 ev)
{
    vf2 em = ev * (vf2){NSLOPE, NSLOPE};     // v_pk_mul_f32
    return (vf2){__builtin_amdgcn_exp2f(fmaxf(ev.x, em.x)),
                 __builtin_amdgcn_exp2f(fmaxf(ev.y, em.y))};
}

// butterfly sum over lane bit 5. r3/r4 tried v_permlane32_swap_b32 inline
// asm (VALU pipe) and FAILED correctness twice: hand-written permlane in an
// asm block is exposed to VALU->permlane wait-state hazards the compiler
// normally fences with s_nop; corruption varied with surrounding codegen.
// Cost of the safe form: ~21 extra ds_bpermute/wave (~2% of DS budget).
__device__ __forceinline__ float bfly32_sum(float s)
{
    return s + __shfl_xor(s, 32);
}

// ---------------------------------------------------------------------------
// Prep (1 block)
// ---------------------------------------------------------------------------
__global__ void prep_kernel(const float* __restrict__ c1w,
                            const float* __restrict__ g1, const float* __restrict__ b1,
                            const float* __restrict__ m1, const float* __restrict__ v1,
                            const float* __restrict__ W,
                            const float* __restrict__ asrc, const float* __restrict__ adst,
                            const float* __restrict__ bias,
                            const float* __restrict__ g2, const float* __restrict__ b2,
                            const float* __restrict__ m2, const float* __restrict__ v2,
                            const int* __restrict__ ei, int ne, float* __restrict__ ws)
{
    const int tid = threadIdx.x;
    __shared__ float sweff[1024];
    __shared__ float schl[32];
    __shared__ int isrcp_i[64 * MDI];
    __shared__ int outdst_i[64 * MDO];
    __shared__ int inslot[64], outslot[64];

    for (int idx = tid; idx < 1024; idx += TPB) {
        int k = idx >> 5, f2 = idx & 31;
        float s = 0.f;
        for (int f = 0; f < 16; f++) {
            float a1 = g1[f] * rsqrtf(v1[f] + EPSc);
            s += a1 * W[f * 32 + f2] * c1w[f * 32 + k];
        }
        ws[OW_WEFF + idx] = s;
        ws[OW_WFT + f2 * 32 + k] = s;
        sweff[idx] = s;
    }
    for (int f2 = tid; f2 < 32; f2 += TPB) {
        float s = 0.f;
        for (int f = 0; f < 16; f++) {
            float a1 = g1[f] * rsqrtf(v1[f] + EPSc);
            s = fmaf(b1[f] - a1 * m1[f], W[f * 32 + f2], s);
        }
        ws[OW_CHL + f2] = s;
        schl[f2] = s;
        float a2 = g2[f2] * rsqrtf(v2[f2] + EPSc);
        ws[OW_A2C2 + f2] = a2;
        ws[OW_A2C2 + 32 + f2] = b2[f2] + a2 * (bias[f2] - m2[f2]);
    }

    // graph lists WITHOUT self-edges (self handled in-register in gat)
    for (int i = tid; i < 64 * MDI; i += TPB) isrcp_i[i] = 0;
    for (int i = tid; i < 64 * MDO; i += TPB) outdst_i[i] = 0;
    if (tid < 64) { inslot[tid] = 0; outslot[tid] = 0; }
    __syncthreads();
    for (int e = tid; e < ne; e += TPB) {
        int s = ei[e], d = ei[ne + e];
        if (s == d) continue;
        int pi = atomicAdd(&inslot[d], 1);
        if (pi < 15) isrcp_i[d * MDI + pi] = s;
        int po = atomicAdd(&outslot[s], 1);
        if (po < MDO) outdst_i[s * MDO + po] = d;
    }
    __syncthreads();

    if (tid < 128) {
        int k = tid >> 2, h = tid & 3;
        float s1 = 0.f, s2 = 0.f;
        for (int o = 0; o < 8; o++) {
            float wv = sweff[k * 32 + h * 8 + o];
            s1 = fmaf(asrc[h * 8 + o], wv, s1);
            s2 = fmaf(adst[h * 8 + o], wv, s2);
        }
        ws[OW_WES + h * 32 + k] = s1;
        ws[OW_WED + h * 32 + k] = s2;
    }
    if (tid < 4) {
        float s1 = 0.f, s2 = 0.f;
        for (int o = 0; o < 8; o++) {
            float cv = schl[tid * 8 + o];
            s1 = fmaf(asrc[tid * 8 + o], cv, s1);
            s2 = fmaf(adst[tid * 8 + o], cv, s2);
        }
        ws[OW_CES + tid] = s1;
        ws[OW_CES + 4 + tid] = s2;
    }
    // pack graph to bytes
    unsigned char* gb = (unsigned char*)(ws + OW_GRAPH);
    for (int i = tid; i < 64 * MDI; i += TPB) gb[i] = (unsigned char)isrcp_i[i];
    for (int i = tid; i < 64 * MDO; i += TPB) gb[1088 + i] = (unsigned char)outdst_i[i];
    __syncthreads();
    if (tid < 64) {
        int id = inslot[tid] < 15 ? inslot[tid] : 15;
        int od = outslot[tid] < MDO ? outslot[tid] : MDO;
        gb[tid * MDI + 15] = (unsigned char)id;   // indeg packed into list byte 15
        gb[1024 + tid] = (unsigned char)id;
        gb[1600 + tid] = (unsigned char)od;
    }
    __syncthreads();
    if (tid == 0) {
        int mi = 0;
        for (int d = 0; d < 64; d++) {
            int a = gb[1024 + d];
            mi = a > mi ? a : mi;
        }
        gb[1664] = (unsigned char)mi;
        gb[1665] = 0;
    }
}

// ---------------------------------------------------------------------------
// Fused conv1+bn1+GAT + mean(v) + bn2+elu+pool8.  wave = head, lane = node.
// ---------------------------------------------------------------------------
__global__ __launch_bounds__(TPB, 4) void gat_kernel(
    const float* __restrict__ x,
    const float* __restrict__ wfTp,
    const float* __restrict__ chlp,
    const float* __restrict__ cesg,
    const float* __restrict__ wesg,
    const float* __restrict__ wedg,
    const float* __restrict__ a2c2,
    const int* __restrict__ graphi,
    float* __restrict__ pout)
{
    __shared__ __align__(16) float sm[L_TOT];
    unsigned char* gb = (unsigned char*)&sm[L_GR];

    const int tid  = threadIdx.x;
    const int b    = blockIdx.x / 192;
    const int tile = blockIdx.x % 192;
    const int t0   = tile * 8;

    const int h = tid >> 6, v = tid & 63;   // wave = head, lane = node

    // ---- S: stage graph + xT (coalesced global, swizzled LDS writes) ----
    for (int idx = tid; idx < GB_INTS; idx += TPB) ((int*)&sm[L_GR])[idx] = graphi[idx];
    for (int idx = tid; idx < 2560; idx += TPB) {
        const int vv = idx / 40, j = idx % 40;   // consecutive lanes: consecutive t
        float val = 1.0f;
        if (j < 39) {
            const int t = t0 - 15 + j;
            val = (t >= 0 && t < Tc) ? x[(b * 64 + vv) * Tc + t] : 0.f;
        }
        sm[xt_idx(j, vv >> 2, vv & 3)] = val;
    }
    __syncthreads();

    const int hs = __builtin_amdgcn_readfirstlane(h);
    const float* wesh = wesg + hs * 32;
    const float* wedh = wedg + hs * 32;

    // ---- Phase A: es/ed convs (register ring; weights via s_load) ----
    float aes[8], aed[8];
    {
        const int g = v >> 2, lo = v & 3;
        const float cesh = cesg[hs], cedh = cesg[4 + hs];
        #pragma unroll
        for (int t = 0; t < 8; t++) { aes[t] = cesh; aed[t] = cedh; }
        float xr[8];
        #pragma unroll
        for (int q = 0; q < 7; q++) xr[q] = sm[xt_idx(q, g, lo)];
        #pragma unroll
        for (int k = 0; k < 32; k++) {
            xr[(k + 7) & 7] = sm[xt_idx(k + 7, g, lo)];
            const float wek = wesh[k];
            const float wdk = wedh[k];
            #pragma unroll
            for (int t = 0; t < 8; t++) {
                const float xv = xr[(k + t) & 7];
                aes[t] = fmaf(xv, wek, aes[t]);
                aed[t] = fmaf(xv, wdk, aed[t]);
            }
        }
    }

    // ---- Phase B: shfl softmax; self-edge in-register; b128 list reads ----
    {
        vf2 aes2[4], aed2[4];
        #pragma unroll
        for (int tp = 0; tp < 4; tp++) {
            aes2[tp] = (vf2){aes[2 * tp] * L2E, aes[2 * tp + 1] * L2E};
            aed2[tp] = (vf2){aed[2 * tp] * L2E, aed[2 * tp + 1] * L2E};
        }

        const int4 il = *(const int4*)(gb + v * MDI);            // ds_read_b128
        const unsigned ow = *(const unsigned*)(gb + 1088 + v * MDO);
        const int indeg = ((unsigned)il.w) >> 24;                // byte 15
        int mdin = gb[1664];
        mdin = __builtin_amdgcn_readfirstlane(mdin);             // uniform bound
        const unsigned iw[4] = {(unsigned)il.x, (unsigned)il.y,
                                (unsigned)il.z, (unsigned)il.w};

        // self-edge term (no cross-lane transport)
        vf2 Es2[4], den2[4];
        #pragma unroll
        for (int tp = 0; tp < 4; tp++) {
            Es2[tp] = lexp2v(aes2[tp] + aed2[tp]);
            den2[tp] = Es2[tp];
        }
        // in-gather over non-self in-edges (uniform trip count mdin <= 15)
        #pragma unroll
        for (int e = 0; e < 15; e++) {
            if (e < mdin) {
                const int s = (iw[e >> 2] >> ((e & 3) * 8)) & 0xFF;
                const float valid = (e < indeg) ? 1.f : 0.f;
                #pragma unroll
                for (int tp = 0; tp < 4; tp++) {
                    vf2 ev = shfl64v(aes2[tp], s) + aed2[tp];
                    vf2 E = lexp2v(ev);
                    den2[tp].x += valid * E.x;
                    den2[tp].y += valid * E.y;
                }
            }
        }
        vf2 rden2[4], wb2[4];
        #pragma unroll
        for (int tp = 0; tp < 4; tp++) {
            float dx = den2[tp].x, dy = den2[tp].y;
            float rx = __builtin_amdgcn_rcpf(dx); rx = rx * (2.f - dx * rx);
            float ry = __builtin_amdgcn_rcpf(dy); ry = ry * (2.f - dy * ry);
            rden2[tp] = (vf2){rx, ry};
            wb2[tp] = Es2[tp] * rden2[tp];           // self contribution
        }
        // out-edges: exactly 4 (KNN, self removed)
        #pragma unroll
        for (int j = 0; j < 4; j++) {
            const int d = (ow >> (j * 8)) & 0xFF;
            #pragma unroll
            for (int tp = 0; tp < 4; tp++) {
                vf2 ev = aes2[tp] + shfl64v(aed2[tp], d);
                vf2 E = lexp2v(ev);
                vf2 rv = shfl64v(rden2[tp], d);
                wb2[tp].x = fmaf(E.x, rv.x, wb2[tp].x);
                wb2[tp].y = fmaf(E.y, rv.y, wb2[tp].y);
            }
        }
        #pragma unroll
        for (int tp = 0; tp < 4; tp++) {
            sm[L_WB + h * 544 + (2 * tp) * 68 + v]     = wb2[tp].x;
            sm[L_WB + h * 544 + (2 * tp + 1) * 68 + v] = wb2[tp].y;
        }
    }
    __asm__ volatile("s_waitcnt lgkmcnt(0)" ::: "memory");   // wave-local drain

    // ---- Phase C: y[t,c] = sum_v wb[t,v]*xT[c,v]
    //      lane = (cg 8) x (th 2) x (kq 4): 5c x 4t x 16v per lane
    //      K-quarter reduce: shfl_xor(16) + shfl_xor(32) ----
    {
        const int cg = v & 7;          // c rows cg*5 .. cg*5+4
        const int th = (v >> 3) & 1;   // t rows th*4 .. th*4+3
        const int kq = v >> 4;         // v cols kq*16 .. kq*16+15

        vf2 yp[4][5];
        #pragma unroll
        for (int i = 0; i < 4; i++)
            #pragma unroll
            for (int q = 0; q < 5; q++) yp[i][q] = (vf2){0.f, 0.f};

        const float* wbbase = &sm[L_WB + h * 544 + (th * 4) * 68];
        #pragma unroll
        for (int v4 = 0; v4 < 4; v4++) {
            const int vcol = kq * 16 + v4 * 4;      // unswizzled granule col
            float4 wrow[4];
            #pragma unroll
            for (int i = 0; i < 4; i++)
                wrow[i] = *(const float4*)(wbbase + i * 68 + vcol);
            #pragma unroll
            for (int q = 0; q < 5; q++) {
                const int row = cg * 5 + q;
                const int mg = ((kq * 4 + v4 + row) & 15) << 2;   // swizzled
                const float4 x4 = *(const float4*)(&sm[L_XT + row * 68 + mg]);
                const vf2 x01 = (vf2){x4.x, x4.y}, x23 = (vf2){x4.z, x4.w};
                #pragma unroll
                for (int i = 0; i < 4; i++) {
                    const vf2 w01 = (vf2){wrow[i].x, wrow[i].y};
                    const vf2 w23 = (vf2){wrow[i].z, wrow[i].w};
                    yp[i][q] += w01 * x01;          // v_pk_fma_f32
                    yp[i][q] += w23 * x23;
                }
            }
        }
        float ya[4][5];
        #pragma unroll
        for (int i = 0; i < 4; i++)
            #pragma unroll
            for (int q = 0; q < 5; q++) {
                float s = yp[i][q].x + yp[i][q].y;
                s += __shfl_xor(s, 16);             // kq bit 0
                ya[i][q] = bfly32_sum(s);           // kq bit 1
            }
        // each lane writes row t = th*4 + kq (static-index select over kq)
        float* yw = &sm[L_Y + h * 328 + (th * 4 + kq) * 41 + cg * 5];
        #pragma unroll
        for (int q = 0; q < 5; q++) {
            float a01 = (kq & 1) ? ya[1][q] : ya[0][q];
            float a23 = (kq & 1) ? ya[3][q] : ya[2][q];
            yw[q] = (kq & 2) ? a23 : a01;
        }
    }
    // wave-local: wave h reads only its own L_Y region; drain suffices.
    __asm__ volatile("s_waitcnt lgkmcnt(0)" ::: "memory");

    // ---- Phase D+E fused (wave-local): g -> bn2+elu -> pool8 ----
    {
        const int t = v >> 3, o = v & 7;
        const int f2d = h * 8 + o;
        const float4* wf4 = (const float4*)(wfTp + f2d * 32);

        const float* yr = &sm[L_Y + h * 328 + t * 41];
        float acc = chlp[f2d] * yr[39];
        #pragma unroll
        for (int k4 = 0; k4 < 8; k4++) {
            const float4 w = wf4[k4];
            acc = fmaf(w.x, yr[t + 4 * k4 + 0],
                  fmaf(w.y, yr[t + 4 * k4 + 1],
                  fmaf(w.z, yr[t + 4 * k4 + 2],
                  fmaf(w.w, yr[t + 4 * k4 + 3], acc))));
        }

        const float a2 = a2c2[f2d], c2 = a2c2[32 + f2d];
        float y = fmaf(a2, acc * (1.f / 64.f), c2);
        y = y > 0.f ? y : __expf(y) - 1.f;
        y += __shfl_xor(y, 8);
        y += __shfl_xor(y, 16);
        y = bfly32_sum(y);
        if (v < 8)
            pout[(b * T2c + tile) * 32 + h * 8 + v] = y * 0.125f;
    }
}

// ---------------------------------------------------------------------------
// conv3(K=16,'same') + bn3 + elu + avgpool(4): p[B,192,32] -> out[B,32,48].
// ---------------------------------------------------------------------------
__global__ __launch_bounds__(TPB) void conv3_kernel(const float* __restrict__ pp,
                                                    const float* __restrict__ w3,
                                                    const float* __restrict__ g3,
                                                    const float* __restrict__ b3,
                                                    const float* __restrict__ m3,
                                                    const float* __restrict__ v3,
                                                    float* __restrict__ outp)
{
    __shared__ float pl[63 * 32];
    __shared__ float q[48 * 32];
    const int tid = threadIdx.x;
    const int b = blockIdx.x >> 2, cc = blockIdx.x & 3;

    for (int idx = tid; idx < 63 * 32; idx += TPB) {
        int r = idx >> 5, f2 = idx & 31;
        int tog = cc * 48 - 7 + r;
        pl[idx] = (tog >= 0 && tog < T2c) ? pp[(b * T2c + tog) * 32 + f2] : 0.f;
    }
    __syncthreads();

    const int f2o = tid & 31, grp = tid >> 5;
    const int tb = grp * 6;
    float acc[6] = { 0.f, 0.f, 0.f, 0.f, 0.f, 0.f };
    for (int f2i = 0; f2i < 32; f2i++) {
        float seg[21];
        #pragma unroll
        for (int r = 0; r < 21; r++) seg[r] = pl[(tb + r) * 32 + f2i];
        const float4* wrow = (const float4*)(w3 + (f2o * 32 + f2i) * 16);
        #pragma unroll
        for (int k4 = 0; k4 < 4; k4++) {
            const float4 w4 = wrow[k4];
            #pragma unroll
            for (int j = 0; j < 6; j++) {
                acc[j] = fmaf(seg[j + k4 * 4 + 0], w4.x,
                         fmaf(seg[j + k4 * 4 + 1], w4.y,
                         fmaf(seg[j + k4 * 4 + 2], w4.z,
                         fmaf(seg[j + k4 * 4 + 3], w4.w, acc[j]))));
            }
        }
    }
    const float a3 = g3[f2o] * rsqrtf(v3[f2o] + EPSc);
    const float c3 = b3[f2o] - a3 * m3[f2o];
    #pragma unroll
    for (int j = 0; j < 6; j++) {
        float y = fmaf(a3, acc[j], c3);
        y = y > 0.f ? y : __expf(y) - 1.f;
        q[(tb + j) * 32 + f2o] = y;
    }
    __syncthreads();
    for (int idx = tid; idx < 12 * 32; idx += TPB) {
        int t4 = idx >> 5, f2 = idx & 31;
        int r0 = t4 * 4;
        float s = q[r0 * 32 + f2] + q[(r0 + 1) * 32 + f2] +
                  q[(r0 + 2) * 32 + f2] + q[(r0 + 3) * 32 + f2];
        outp[(b * 32 + f2) * 48 + cc * 12 + t4] = s * 0.25f;
    }
}

// ---------------------------------------------------------------------------
extern "C" void kernel_launch(void* const* d_in, const int* in_sizes, int n_in,
                              void* d_out, int out_size, void* d_ws, size_t ws_size,
                              hipStream_t stream)
{
    const float* x    = (const float*)d_in[0];
    const float* c1w  = (const float*)d_in[1];
    const float* g1   = (const float*)d_in[2];
    const float* b1   = (const float*)d_in[3];
    const float* m1   = (const float*)d_in[4];
    const float* v1   = (const float*)d_in[5];
    const float* W    = (const float*)d_in[6];
    const float* asrc = (const float*)d_in[7];
    const float* adst = (const float*)d_in[8];
    const float* bias = (const float*)d_in[9];
    const float* g2   = (const float*)d_in[10];
    const float* b2   = (const float*)d_in[11];
    const float* m2   = (const float*)d_in[12];
    const float* v2   = (const float*)d_in[13];
    const float* w3   = (const float*)d_in[14];
    const float* g3   = (const float*)d_in[15];
    const float* b3   = (const float*)d_in[16];
    const float* m3   = (const float*)d_in[17];
    const float* v3   = (const float*)d_in[18];
    const int*   ei   = (const int*)d_in[19];
    const int    ne   = in_sizes[19] / 2;

    float* ws = (float*)d_ws;

    prep_kernel<<<1, TPB, 0, stream>>>(c1w, g1, b1, m1, v1, W, asrc, adst,
                                       bias, g2, b2, m2, v2, ei, ne, ws);

    gat_kernel<<<Bc * T2c, TPB, 0, stream>>>(x,
                                             ws + OW_WFT, ws + OW_CHL,
                                             ws + OW_CES,
                                             ws + OW_WES, ws + OW_WED,
                                             ws + OW_A2C2,
                                             (const int*)(ws + OW_GRAPH),
                                             ws + OW_P);

    conv3_kernel<<<Bc * 4, TPB, 0, stream>>>(ws + OW_P, w3, g3, b3, m3, v3,
                                             (float*)d_out);
}

// Round 6
// 165.967 us; speedup vs baseline: 1.0123x; 1.0123x over previous
//
#include <hip/hip_runtime.h>
#include <math.h>

#define TPB 256

// Problem constants
constexpr int Bc = 16, Tc = 1536;
constexpr int T2c = 192;           // T / P1
constexpr float EPSc = 1e-5f;
constexpr float NSLOPE = 0.2f;
constexpr int MDI = 16;            // padded in-degree stride (bytes); byte15 = indeg
constexpr int MDO = 8;             // padded out-degree stride (bytes)
constexpr float L2E = 1.4426950408889634f;

typedef float vf2 __attribute__((ext_vector_type(2)));

// Workspace layout (float offsets)
constexpr int OW_WEFF = 0;         // [32 k][32 f2]
constexpr int OW_CHL  = 1024;      // [32]
constexpr int OW_CES  = 1056;      // ces[4] | ced[4]
constexpr int OW_WES  = 1064;      // [4 h][32 k]
constexpr int OW_WED  = 1192;      // [4 h][32 k]
constexpr int OW_A2C2 = 1320;      // a2[32] | c2[32] folded bn2 affine
constexpr int OW_WFT  = 1384;      // [32 f2][32 k]  transposed weff
constexpr int OW_GRAPH= 2408;      // 417 ints packed byte graph
constexpr int OW_P    = 2825;      // [B][192][32]

// Packed graph byte offsets (SELF-EDGES EXCLUDED from lists):
//   [0,1024)    in-lists  isrc[d*16+e], e<15 (pad 0); byte d*16+15 = indeg(no-self)
//   [1024,1088) indeg[d]  (no-self, clamped 15)
//   [1088,1600) out-lists outdst[v*8+j], exactly 4 entries (KNN), pads 0
//   [1600,1664) outdeg[v]
//   [1664] max in-degree (no-self)
constexpr int GB_INTS = 417;

// gat LDS layout (float offsets)
constexpr int L_XT  = 0;           // xT [40 c][68 v]; row 39 = ones; ROTATION-SWIZZLED
constexpr int L_WB  = 2720;        // [4 h][8 t][68 v]
constexpr int L_Y   = 4896;        // [4 h][8 t][41]; per-head 328 floats.
                                   // During B: first 256 floats of own head's
                                   // region = wave-local logit-gather scratch.
constexpr int L_GR  = 6208;        // 417 ints packed graph
constexpr int L_TOT = 6625;        // 26.5 KB -> 6 blocks/CU

#define LGKM0() __asm__ volatile("s_waitcnt lgkmcnt(0)" ::: "memory")

// XT swizzle: column granule rotated by row: g' = (g + row) & 15.
__device__ __forceinline__ int xt_idx(int row, int g, int lo)
{
    return L_XT + row * 68 + (((g + row) & 15) << 2) + lo;
}

// exp2(leaky(z)) with logit pre-scaled by log2(e)
__device__ __forceinline__ float lexp2(float z)
{
    return __builtin_amdgcn_exp2f(fmaxf(z, NSLOPE * z));
}

// Butterfly sums via gfx950 permlane-swap BUILTINS (VALU pipe, compiler
// handles operand allocation + wait-states; r3/r4 hand-asm versions were
// broken). With both inputs = s the two results sum to s + s[lane^K] in
// every lane. Fallback: ds_bpermute shfl_xor (DS pipe, correct but slower).
__device__ __forceinline__ float bfly16_sum(float s)
{
#if __has_builtin(__builtin_amdgcn_permlane16_swap)
    unsigned u = __builtin_bit_cast(unsigned, s);
    auto r = __builtin_amdgcn_permlane16_swap(u, u, false, false);
    return __builtin_bit_cast(float, (unsigned)r[0]) +
           __builtin_bit_cast(float, (unsigned)r[1]);
#else
    return s + __shfl_xor(s, 16);
#endif
}

__device__ __forceinline__ float bfly32_sum(float s)
{
#if __has_builtin(__builtin_amdgcn_permlane32_swap)
    unsigned u = __builtin_bit_cast(unsigned, s);
    auto r = __builtin_amdgcn_permlane32_swap(u, u, false, false);
    return __builtin_bit_cast(float, (unsigned)r[0]) +
           __builtin_bit_cast(float, (unsigned)r[1]);
#else
    return s + __shfl_xor(s, 32);
#endif
}

// ---------------------------------------------------------------------------
// Prep (1 block)
// ---------------------------------------------------------------------------
__global__ void prep_kernel(const float* __restrict__ c1w,
                            const float* __restrict__ g1, const float* __restrict__ b1,
                            const float* __restrict__ m1, const float* __restrict__ v1,
                            const float* __restrict__ W,
                            const float* __restrict__ asrc, const float* __restrict__ adst,
                            const float* __restrict__ bias,
                            const float* __restrict__ g2, const float* __restrict__ b2,
                            const float* __restrict__ m2, const float* __restrict__ v2,
                            const int* __restrict__ ei, int ne, float* __restrict__ ws)
{
    const int tid = threadIdx.x;
    __shared__ float sweff[1024];
    __shared__ float schl[32];
    __shared__ int isrcp_i[64 * MDI];
    __shared__ int outdst_i[64 * MDO];
    __shared__ int inslot[64], outslot[64];

    for (int idx = tid; idx < 1024; idx += TPB) {
        int k = idx >> 5, f2 = idx & 31;
        float s = 0.f;
        for (int f = 0; f < 16; f++) {
            float a1 = g1[f] * rsqrtf(v1[f] + EPSc);
            s += a1 * W[f * 32 + f2] * c1w[f * 32 + k];
        }
        ws[OW_WEFF + idx] = s;
        ws[OW_WFT + f2 * 32 + k] = s;
        sweff[idx] = s;
    }
    for (int f2 = tid; f2 < 32; f2 += TPB) {
        float s = 0.f;
        for (int f = 0; f < 16; f++) {
            float a1 = g1[f] * rsqrtf(v1[f] + EPSc);
            s = fmaf(b1[f] - a1 * m1[f], W[f * 32 + f2], s);
        }
        ws[OW_CHL + f2] = s;
        schl[f2] = s;
        float a2 = g2[f2] * rsqrtf(v2[f2] + EPSc);
        ws[OW_A2C2 + f2] = a2;
        ws[OW_A2C2 + 32 + f2] = b2[f2] + a2 * (bias[f2] - m2[f2]);
    }

    // graph lists WITHOUT self-edges (self handled in-register in gat)
    for (int i = tid; i < 64 * MDI; i += TPB) isrcp_i[i] = 0;
    for (int i = tid; i < 64 * MDO; i += TPB) outdst_i[i] = 0;
    if (tid < 64) { inslot[tid] = 0; outslot[tid] = 0; }
    __syncthreads();
    for (int e = tid; e < ne; e += TPB) {
        int s = ei[e], d = ei[ne + e];
        if (s == d) continue;
        int pi = atomicAdd(&inslot[d], 1);
        if (pi < 15) isrcp_i[d * MDI + pi] = s;
        int po = atomicAdd(&outslot[s], 1);
        if (po < MDO) outdst_i[s * MDO + po] = d;
    }
    __syncthreads();

    if (tid < 128) {
        int k = tid >> 2, h = tid & 3;
        float s1 = 0.f, s2 = 0.f;
        for (int o = 0; o < 8; o++) {
            float wv = sweff[k * 32 + h * 8 + o];
            s1 = fmaf(asrc[h * 8 + o], wv, s1);
            s2 = fmaf(adst[h * 8 + o], wv, s2);
        }
        ws[OW_WES + h * 32 + k] = s1;
        ws[OW_WED + h * 32 + k] = s2;
    }
    if (tid < 4) {
        float s1 = 0.f, s2 = 0.f;
        for (int o = 0; o < 8; o++) {
            float cv = schl[tid * 8 + o];
            s1 = fmaf(asrc[tid * 8 + o], cv, s1);
            s2 = fmaf(adst[tid * 8 + o], cv, s2);
        }
        ws[OW_CES + tid] = s1;
        ws[OW_CES + 4 + tid] = s2;
    }
    // pack graph to bytes
    unsigned char* gb = (unsigned char*)(ws + OW_GRAPH);
    for (int i = tid; i < 64 * MDI; i += TPB) gb[i] = (unsigned char)isrcp_i[i];
    for (int i = tid; i < 64 * MDO; i += TPB) gb[1088 + i] = (unsigned char)outdst_i[i];
    __syncthreads();
    if (tid < 64) {
        int id = inslot[tid] < 15 ? inslot[tid] : 15;
        int od = outslot[tid] < MDO ? outslot[tid] : MDO;
        gb[tid * MDI + 15] = (unsigned char)id;   // indeg packed into list byte 15
        gb[1024 + tid] = (unsigned char)id;
        gb[1600 + tid] = (unsigned char)od;
    }
    __syncthreads();
    if (tid == 0) {
        int mi = 0;
        for (int d = 0; d < 64; d++) {
            int a = gb[1024 + d];
            mi = a > mi ? a : mi;
        }
        gb[1664] = (unsigned char)mi;
        gb[1665] = 0;
    }
}

// ---------------------------------------------------------------------------
// Fused conv1+bn1+GAT + mean(v) + bn2+elu+pool8.  wave = head, lane = node.
//   B softmax now uses WIDE-LDS GATHER instead of ds_bpermute:
//   stage this head's logits in a wave-local scratch (own L_Y region, dead
//   until C) and gather per-edge quads with ds_read_b128 (4 t / inst vs
//   32 bits / bpermute). Two t-halves for the in-gather (aes quads), four
//   t-quarters for the out-gather ({ed,ed,rden,rden} quads).
// ---------------------------------------------------------------------------
__global__ __launch_bounds__(TPB, 4) void gat_kernel(
    const float* __restrict__ x,
    const float* __restrict__ wfTp,
    const float* __restrict__ chlp,
    const float* __restrict__ cesg,
    const float* __restrict__ wesg,
    const float* __restrict__ wedg,
    const float* __restrict__ a2c2,
    const int* __restrict__ graphi,
    float* __restrict__ pout)
{
    __shared__ __align__(16) float sm[L_TOT];
    unsigned char* gb = (unsigned char*)&sm[L_GR];

    const int tid  = threadIdx.x;
    const int b    = blockIdx.x / 192;
    const int tile = blockIdx.x % 192;
    const int t0   = tile * 8;

    const int h = tid >> 6, v = tid & 63;   // wave = head, lane = node

    // ---- S: stage graph + xT (coalesced global, swizzled LDS writes) ----
    for (int idx = tid; idx < GB_INTS; idx += TPB) ((int*)&sm[L_GR])[idx] = graphi[idx];
    for (int idx = tid; idx < 2560; idx += TPB) {
        const int vv = idx / 40, j = idx % 40;   // consecutive lanes: consecutive t
        float val = 1.0f;
        if (j < 39) {
            const int t = t0 - 15 + j;
            val = (t >= 0 && t < Tc) ? x[(b * 64 + vv) * Tc + t] : 0.f;
        }
        sm[xt_idx(j, vv >> 2, vv & 3)] = val;
    }
    __syncthreads();

    const int hs = __builtin_amdgcn_readfirstlane(h);
    const float* wesh = wesg + hs * 32;
    const float* wedh = wedg + hs * 32;

    // ---- Phase A: es/ed convs (register ring; weights via s_load) ----
    float aes[8], aed[8];
    {
        const int g = v >> 2, lo = v & 3;
        const float cesh = cesg[hs], cedh = cesg[4 + hs];
        #pragma unroll
        for (int t = 0; t < 8; t++) { aes[t] = cesh; aed[t] = cedh; }
        float xr[8];
        #pragma unroll
        for (int q = 0; q < 7; q++) xr[q] = sm[xt_idx(q, g, lo)];
        #pragma unroll
        for (int k = 0; k < 32; k++) {
            xr[(k + 7) & 7] = sm[xt_idx(k + 7, g, lo)];
            const float wek = wesh[k];
            const float wdk = wedh[k];
            #pragma unroll
            for (int t = 0; t < 8; t++) {
                const float xv = xr[(k + t) & 7];
                aes[t] = fmaf(xv, wek, aes[t]);
                aed[t] = fmaf(xv, wdk, aed[t]);
            }
        }
        // exp2-domain prescale
        #pragma unroll
        for (int t = 0; t < 8; t++) { aes[t] *= L2E; aed[t] *= L2E; }
    }

    // ---- Phase B: softmax via wave-local wide-LDS gather ----
    {
        float* esL = &sm[L_Y + h * 328];   // own head's scratch (256 of 328)

        const int4 il = *(const int4*)(gb + v * MDI);            // ds_read_b128
        const unsigned ow = *(const unsigned*)(gb + 1088 + v * MDO);
        const int indeg = (int)(((unsigned)il.w) >> 24);         // byte 15
        const int mdin = __builtin_amdgcn_readfirstlane((int)gb[1664]);
        const unsigned iw[4] = {(unsigned)il.x, (unsigned)il.y,
                                (unsigned)il.z, (unsigned)il.w};

        // self-edge term (no transport)
        float den[8], Eself[8];
        #pragma unroll
        for (int t = 0; t < 8; t++) {
            Eself[t] = lexp2(aes[t] + aed[t]);
            den[t] = Eself[t];
        }

        // in-gather: two t-halves; 1 b128 read per edge = 4 t's at once
        #pragma unroll
        for (int hf = 0; hf < 2; hf++) {
            *(float4*)(esL + v * 4) = (float4){aes[hf * 4 + 0], aes[hf * 4 + 1],
                                              aes[hf * 4 + 2], aes[hf * 4 + 3]};
            LGKM0();
            #pragma unroll
            for (int e = 0; e < 15; e++) {
                if (e < mdin) {                  // wave-uniform bound
                    const int s = (int)((iw[e >> 2] >> ((e & 3) * 8)) & 0xFF);
                    const float4 e4 = *(const float4*)(esL + s * 4);
                    const float valid = (e < indeg) ? 1.f : 0.f;
                    den[hf * 4 + 0] += valid * lexp2(e4.x + aed[hf * 4 + 0]);
                    den[hf * 4 + 1] += valid * lexp2(e4.y + aed[hf * 4 + 1]);
                    den[hf * 4 + 2] += valid * lexp2(e4.z + aed[hf * 4 + 2]);
                    den[hf * 4 + 3] += valid * lexp2(e4.w + aed[hf * 4 + 3]);
                }
            }
            LGKM0();   // reads done before scratch is overwritten
        }

        float rden[8], wb[8];
        #pragma unroll
        for (int t = 0; t < 8; t++) {
            float r = __builtin_amdgcn_rcpf(den[t]);
            r = r * (2.f - den[t] * r);          // Newton step, rel err ~1e-12
            rden[t] = r;
            wb[t] = Eself[t] * r;                // self contribution
        }

        // out-gather: four t-quarters; {ed,ed,rden,rden} quad per node,
        // 1 b128 read per out-edge (exactly 4 KNN edges)
        #pragma unroll
        for (int qt = 0; qt < 4; qt++) {
            *(float4*)(esL + v * 4) = (float4){aed[2 * qt], aed[2 * qt + 1],
                                               rden[2 * qt], rden[2 * qt + 1]};
            LGKM0();
            #pragma unroll
            for (int j = 0; j < 4; j++) {
                const int d = (int)((ow >> (j * 8)) & 0xFF);
                const float4 g4 = *(const float4*)(esL + d * 4);
                wb[2 * qt + 0] = fmaf(lexp2(aes[2 * qt + 0] + g4.x), g4.z, wb[2 * qt + 0]);
                wb[2 * qt + 1] = fmaf(lexp2(aes[2 * qt + 1] + g4.y), g4.w, wb[2 * qt + 1]);
            }
            LGKM0();
        }

        #pragma unroll
        for (int t = 0; t < 8; t++)
            sm[L_WB + h * 544 + t * 68 + v] = wb[t];
    }
    LGKM0();   // wave-local drain before C reads L_WB

    // ---- Phase C: y[t,c] = sum_v wb[t,v]*xT[c,v]
    //      lane = (cg 8) x (th 2) x (kq 4): 5c x 4t x 16v per lane
    //      K-quarter reduce: permlane16 + permlane32 butterflies (VALU) ----
    {
        const int cg = v & 7;          // c rows cg*5 .. cg*5+4
        const int th = (v >> 3) & 1;   // t rows th*4 .. th*4+3
        const int kq = v >> 4;         // v cols kq*16 .. kq*16+15

        vf2 yp[4][5];
        #pragma unroll
        for (int i = 0; i < 4; i++)
            #pragma unroll
            for (int q = 0; q < 5; q++) yp[i][q] = (vf2){0.f, 0.f};

        const float* wbbase = &sm[L_WB + h * 544 + (th * 4) * 68];
        #pragma unroll
        for (int v4 = 0; v4 < 4; v4++) {
            const int vcol = kq * 16 + v4 * 4;      // unswizzled granule col
            float4 wrow[4];
            #pragma unroll
            for (int i = 0; i < 4; i++)
                wrow[i] = *(const float4*)(wbbase + i * 68 + vcol);
            #pragma unroll
            for (int q = 0; q < 5; q++) {
                const int row = cg * 5 + q;
                const int mg = ((kq * 4 + v4 + row) & 15) << 2;   // swizzled
                const float4 x4 = *(const float4*)(&sm[L_XT + row * 68 + mg]);
                const vf2 x01 = (vf2){x4.x, x4.y}, x23 = (vf2){x4.z, x4.w};
                #pragma unroll
                for (int i = 0; i < 4; i++) {
                    const vf2 w01 = (vf2){wrow[i].x, wrow[i].y};
                    const vf2 w23 = (vf2){wrow[i].z, wrow[i].w};
                    yp[i][q] += w01 * x01;          // v_pk_fma_f32
                    yp[i][q] += w23 * x23;
                }
            }
        }
        float ya[4][5];
        #pragma unroll
        for (int i = 0; i < 4; i++)
            #pragma unroll
            for (int q = 0; q < 5; q++) {
                float s = yp[i][q].x + yp[i][q].y;
                ya[i][q] = bfly32_sum(bfly16_sum(s));   // kq bits via permlane
            }
        // each lane writes row t = th*4 + kq (static-index select over kq)
        float* yw = &sm[L_Y + h * 328 + (th * 4 + kq) * 41 + cg * 5];
        #pragma unroll
        for (int q = 0; q < 5; q++) {
            float a01 = (kq & 1) ? ya[1][q] : ya[0][q];
            float a23 = (kq & 1) ? ya[3][q] : ya[2][q];
            yw[q] = (kq & 2) ? a23 : a01;
        }
    }
    // wave-local: wave h reads only its own L_Y region; drain suffices.
    LGKM0();

    // ---- Phase D+E fused (wave-local): g -> bn2+elu -> pool8 ----
    {
        const int t = v >> 3, o = v & 7;
        const int f2d = h * 8 + o;
        const float4* wf4 = (const float4*)(wfTp + f2d * 32);

        const float* yr = &sm[L_Y + h * 328 + t * 41];
        float acc = chlp[f2d] * yr[39];
        #pragma unroll
        for (int k4 = 0; k4 < 8; k4++) {
            const float4 w = wf4[k4];
            acc = fmaf(w.x, yr[t + 4 * k4 + 0],
                  fmaf(w.y, yr[t + 4 * k4 + 1],
                  fmaf(w.z, yr[t + 4 * k4 + 2],
                  fmaf(w.w, yr[t + 4 * k4 + 3], acc))));
        }

        const float a2 = a2c2[f2d], c2 = a2c2[32 + f2d];
        float y = fmaf(a2, acc * (1.f / 64.f), c2);
        y = y > 0.f ? y : __expf(y) - 1.f;
        y += __shfl_xor(y, 8);
        y = bfly32_sum(bfly16_sum(y));
        if (v < 8)
            pout[(b * T2c + tile) * 32 + h * 8 + v] = y * 0.125f;
    }
}

// ---------------------------------------------------------------------------
// conv3(K=16,'same') + bn3 + elu + avgpool(4): p[B,192,32] -> out[B,32,48].
// ---------------------------------------------------------------------------
__global__ __launch_bounds__(TPB) void conv3_kernel(const float* __restrict__ pp,
                                                    const float* __restrict__ w3,
                                                    const float* __restrict__ g3,
                                                    const float* __restrict__ b3,
                                                    const float* __restrict__ m3,
                                                    const float* __restrict__ v3,
                                                    float* __restrict__ outp)
{
    __shared__ float pl[63 * 32];
    __shared__ float q[48 * 32];
    const int tid = threadIdx.x;
    const int b = blockIdx.x >> 2, cc = blockIdx.x & 3;

    for (int idx = tid; idx < 63 * 32; idx += TPB) {
        int r = idx >> 5, f2 = idx & 31;
        int tog = cc * 48 - 7 + r;
        pl[idx] = (tog >= 0 && tog < T2c) ? pp[(b * T2c + tog) * 32 + f2] : 0.f;
    }
    __syncthreads();

    const int f2o = tid & 31, grp = tid >> 5;
    const int tb = grp * 6;
    float acc[6] = { 0.f, 0.f, 0.f, 0.f, 0.f, 0.f };
    for (int f2i = 0; f2i < 32; f2i++) {
        float seg[21];
        #pragma unroll
        for (int r = 0; r < 21; r++) seg[r] = pl[(tb + r) * 32 + f2i];
        const float4* wrow = (const float4*)(w3 + (f2o * 32 + f2i) * 16);
        #pragma unroll
        for (int k4 = 0; k4 < 4; k4++) {
            const float4 w4 = wrow[k4];
            #pragma unroll
            for (int j = 0; j < 6; j++) {
                acc[j] = fmaf(seg[j + k4 * 4 + 0], w4.x,
                         fmaf(seg[j + k4 * 4 + 1], w4.y,
                         fmaf(seg[j + k4 * 4 + 2], w4.z,
                         fmaf(seg[j + k4 * 4 + 3], w4.w, acc[j]))));
            }
        }
    }
    const float a3 = g3[f2o] * rsqrtf(v3[f2o] + EPSc);
    const float c3 = b3[f2o] - a3 * m3[f2o];
    #pragma unroll
    for (int j = 0; j < 6; j++) {
        float y = fmaf(a3, acc[j], c3);
        y = y > 0.f ? y : __expf(y) - 1.f;
        q[(tb + j) * 32 + f2o] = y;
    }
    __syncthreads();
    for (int idx = tid; idx < 12 * 32; idx += TPB) {
        int t4 = idx >> 5, f2 = idx & 31;
        int r0 = t4 * 4;
        float s = q[r0 * 32 + f2] + q[(r0 + 1) * 32 + f2] +
                  q[(r0 + 2) * 32 + f2] + q[(r0 + 3) * 32 + f2];
        outp[(b * 32 + f2) * 48 + cc * 12 + t4] = s * 0.25f;
    }
}

// ---------------------------------------------------------------------------
extern "C" void kernel_launch(void* const* d_in, const int* in_sizes, int n_in,
                              void* d_out, int out_size, void* d_ws, size_t ws_size,
                              hipStream_t stream)
{
    const float* x    = (const float*)d_in[0];
    const float* c1w  = (const float*)d_in[1];
    const float* g1   = (const float*)d_in[2];
    const float* b1   = (const float*)d_in[3];
    const float* m1   = (const float*)d_in[4];
    const float* v1   = (const float*)d_in[5];
    const float* W    = (const float*)d_in[6];
    const float* asrc = (const float*)d_in[7];
    const float* adst = (const float*)d_in[8];
    const float* bias = (const float*)d_in[9];
    const float* g2   = (const float*)d_in[10];
    const float* b2   = (const float*)d_in[11];
    const float* m2   = (const float*)d_in[12];
    const float* v2   = (const float*)d_in[13];
    const float* w3   = (const float*)d_in[14];
    const float* g3   = (const float*)d_in[15];
    const float* b3   = (const float*)d_in[16];
    const float* m3   = (const float*)d_in[17];
    const float* v3   = (const float*)d_in[18];
    const int*   ei   = (const int*)d_in[19];
    const int    ne   = in_sizes[19] / 2;

    float* ws = (float*)d_ws;

    prep_kernel<<<1, TPB, 0, stream>>>(c1w, g1, b1, m1, v1, W, asrc, adst,
                                       bias, g2, b2, m2, v2, ei, ne, ws);

    gat_kernel<<<Bc * T2c, TPB, 0, stream>>>(x,
                                             ws + OW_WFT, ws + OW_CHL,
                                             ws + OW_CES,
                                             ws + OW_WES, ws + OW_WED,
                                             ws + OW_A2C2,
                                             (const int*)(ws + OW_GRAPH),
                                             ws + OW_P);

    conv3_kernel<<<Bc * 4, TPB, 0, stream>>>(ws + OW_P, w3, g3, b3, m3, v3,
                                             (float*)d_out);
}

// Round 7
// 161.210 us; speedup vs baseline: 1.0422x; 1.0295x over previous
//
#include <hip/hip_runtime.h>
#include <math.h>

#define TPB 256

// Problem constants
constexpr int Bc = 16, Tc = 1536;
constexpr int T2c = 192;           // T / P1
constexpr float EPSc = 1e-5f;
constexpr float NSLOPE = 0.2f;
constexpr int MDI = 16;            // padded in-degree stride (bytes); byte15 = indeg
constexpr int MDO = 8;             // padded out-degree stride (bytes)
constexpr float L2E = 1.4426950408889634f;

typedef float vf2 __attribute__((ext_vector_type(2)));

// Workspace layout (float offsets)
constexpr int OW_WEFF = 0;         // [32 k][32 f2]
constexpr int OW_CHL  = 1024;      // [32] (prep-internal; folded into c2)
constexpr int OW_CES  = 1056;      // [4 h][2] {ces,ced} interleaved
constexpr int OW_WSD  = 1064;      // [4 h][32 k][2] {wes,wed} interleaved
constexpr int OW_A2C2 = 1320;      // a2[32] | c2[32] (chl+gat-bias folded)
constexpr int OW_WFT  = 1384;      // [32 f2][32 k]  transposed weff
constexpr int OW_GRAPH= 2408;      // 417 ints packed byte graph (gat reads GLOBAL)
constexpr int OW_P    = 2825;      // [B][192][32]

// Packed graph byte offsets (SELF-EDGES EXCLUDED from lists):
//   [0,1024)    in-lists  isrc[d*16+e], e<15 (pad 0); byte d*16+15 = indeg(no-self)
//   [1024,1088) indeg[d]
//   [1088,1600) out-lists outdst[v*8+j], exactly 4 entries (KNN), pads 0
//   [1600,1664) outdeg[v]
//   [1664] max in-degree (no-self)  (int 416 low byte)

// gat LDS layout (float offsets) — graph no longer staged
constexpr int L_XT  = 0;           // xT [40 c][68 v]; row 39 = ones; ROTATION-SWIZZLED
constexpr int L_WB  = 2720;        // [4 h][8 t][68 v]; first 256/head = B scratch #1
constexpr int L_Y   = 4896;        // [4 h][8 t][41];   first 256/head = B scratch #0
constexpr int L_TOT = 6208;        // 24.8 KB -> 6 blocks/CU

#define LGKM0() __asm__ volatile("s_waitcnt lgkmcnt(0)" ::: "memory")

// XT swizzle: column granule rotated by row: g' = (g + row) & 15.
__device__ __forceinline__ int xt_idx(int row, int g, int lo)
{
    return L_XT + row * 68 + (((g + row) & 15) << 2) + lo;
}

// exp2(leaky(z)) with logit pre-scaled by log2(e)
__device__ __forceinline__ float lexp2(float z)
{
    return __builtin_amdgcn_exp2f(fmaxf(z, NSLOPE * z));
}

// Butterfly sums via gfx950 permlane-swap builtins (VALU pipe; proven r6).
__device__ __forceinline__ float bfly16_sum(float s)
{
#if __has_builtin(__builtin_amdgcn_permlane16_swap)
    unsigned u = __builtin_bit_cast(unsigned, s);
    auto r = __builtin_amdgcn_permlane16_swap(u, u, false, false);
    return __builtin_bit_cast(float, (unsigned)r[0]) +
           __builtin_bit_cast(float, (unsigned)r[1]);
#else
    return s + __shfl_xor(s, 16);
#endif
}

__device__ __forceinline__ float bfly32_sum(float s)
{
#if __has_builtin(__builtin_amdgcn_permlane32_swap)
    unsigned u = __builtin_bit_cast(unsigned, s);
    auto r = __builtin_amdgcn_permlane32_swap(u, u, false, false);
    return __builtin_bit_cast(float, (unsigned)r[0]) +
           __builtin_bit_cast(float, (unsigned)r[1]);
#else
    return s + __shfl_xor(s, 32);
#endif
}

// ---------------------------------------------------------------------------
// Prep (1 block)
// ---------------------------------------------------------------------------
__global__ void prep_kernel(const float* __restrict__ c1w,
                            const float* __restrict__ g1, const float* __restrict__ b1,
                            const float* __restrict__ m1, const float* __restrict__ v1,
                            const float* __restrict__ W,
                            const float* __restrict__ asrc, const float* __restrict__ adst,
                            const float* __restrict__ bias,
                            const float* __restrict__ g2, const float* __restrict__ b2,
                            const float* __restrict__ m2, const float* __restrict__ v2,
                            const int* __restrict__ ei, int ne, float* __restrict__ ws)
{
    const int tid = threadIdx.x;
    __shared__ float sweff[1024];
    __shared__ float schl[32];
    __shared__ int isrcp_i[64 * MDI];
    __shared__ int outdst_i[64 * MDO];
    __shared__ int inslot[64], outslot[64];

    for (int idx = tid; idx < 1024; idx += TPB) {
        int k = idx >> 5, f2 = idx & 31;
        float s = 0.f;
        for (int f = 0; f < 16; f++) {
            float a1 = g1[f] * rsqrtf(v1[f] + EPSc);
            s += a1 * W[f * 32 + f2] * c1w[f * 32 + k];
        }
        ws[OW_WEFF + idx] = s;
        ws[OW_WFT + f2 * 32 + k] = s;
        sweff[idx] = s;
    }
    for (int f2 = tid; f2 < 32; f2 += TPB) {
        float s = 0.f;
        for (int f = 0; f < 16; f++) {
            float a1 = g1[f] * rsqrtf(v1[f] + EPSc);
            s = fmaf(b1[f] - a1 * m1[f], W[f * 32 + f2], s);
        }
        ws[OW_CHL + f2] = s;
        schl[f2] = s;
        float a2 = g2[f2] * rsqrtf(v2[f2] + EPSc);
        ws[OW_A2C2 + f2] = a2;
        // bn2 shift with gat bias AND chl (rowsum==64 exactly) folded in
        ws[OW_A2C2 + 32 + f2] = b2[f2] + a2 * (bias[f2] - m2[f2] + s);
    }

    // graph lists WITHOUT self-edges (self handled in-register in gat)
    for (int i = tid; i < 64 * MDI; i += TPB) isrcp_i[i] = 0;
    for (int i = tid; i < 64 * MDO; i += TPB) outdst_i[i] = 0;
    if (tid < 64) { inslot[tid] = 0; outslot[tid] = 0; }
    __syncthreads();
    for (int e = tid; e < ne; e += TPB) {
        int s = ei[e], d = ei[ne + e];
        if (s == d) continue;
        int pi = atomicAdd(&inslot[d], 1);
        if (pi < 15) isrcp_i[d * MDI + pi] = s;
        int po = atomicAdd(&outslot[s], 1);
        if (po < MDO) outdst_i[s * MDO + po] = d;
    }
    __syncthreads();

    // {wes,wed} interleaved pairs + {ces,ced} pairs
    if (tid < 128) {
        int k = tid >> 2, h = tid & 3;
        float s1 = 0.f, s2 = 0.f;
        for (int o = 0; o < 8; o++) {
            float wv = sweff[k * 32 + h * 8 + o];
            s1 = fmaf(asrc[h * 8 + o], wv, s1);
            s2 = fmaf(adst[h * 8 + o], wv, s2);
        }
        ws[OW_WSD + h * 64 + k * 2]     = s1;
        ws[OW_WSD + h * 64 + k * 2 + 1] = s2;
    }
    if (tid < 4) {
        float s1 = 0.f, s2 = 0.f;
        for (int o = 0; o < 8; o++) {
            float cv = schl[tid * 8 + o];
            s1 = fmaf(asrc[tid * 8 + o], cv, s1);
            s2 = fmaf(adst[tid * 8 + o], cv, s2);
        }
        ws[OW_CES + tid * 2]     = s1;
        ws[OW_CES + tid * 2 + 1] = s2;
    }
    // pack graph to bytes
    unsigned char* gb = (unsigned char*)(ws + OW_GRAPH);
    for (int i = tid; i < 64 * MDI; i += TPB) gb[i] = (unsigned char)isrcp_i[i];
    for (int i = tid; i < 64 * MDO; i += TPB) gb[1088 + i] = (unsigned char)outdst_i[i];
    __syncthreads();
    if (tid < 64) {
        int id = inslot[tid] < 15 ? inslot[tid] : 15;
        int od = outslot[tid] < MDO ? outslot[tid] : MDO;
        gb[tid * MDI + 15] = (unsigned char)id;   // indeg packed into list byte 15
        gb[1024 + tid] = (unsigned char)id;
        gb[1600 + tid] = (unsigned char)od;
    }
    __syncthreads();
    if (tid == 0) {
        int mi = 0;
        for (int d = 0; d < 64; d++) {
            int a = gb[1024 + d];
            mi = a > mi ? a : mi;
        }
        gb[1664] = (unsigned char)mi;
        gb[1665] = 0;
    }
}

// ---------------------------------------------------------------------------
// Fused conv1+bn1+GAT + mean(v) + bn2+elu+pool8.  wave = head, lane = node.
//   Graph lists read straight from GLOBAL (L2-hot), issued at kernel top.
//   Phase B: dual-scratch staging (L_Y + L_WB own-head regions) -> only 6
//   lgkmcnt(0) fences (was 12); in-gather's 22 b128 reads drain once.
// ---------------------------------------------------------------------------
__global__ __launch_bounds__(TPB, 4) void gat_kernel(
    const float* __restrict__ x,
    const float* __restrict__ wfTp,
    const float* __restrict__ cesg,
    const float* __restrict__ wsdg,
    const float* __restrict__ a2c2,
    const int* __restrict__ graphi,
    float* __restrict__ pout)
{
    __shared__ __align__(16) float sm[L_TOT];

    const int tid  = threadIdx.x;
    const int b    = blockIdx.x / 192;
    const int tile = blockIdx.x % 192;
    const int t0   = tile * 8;

    const int h = tid >> 6, v = tid & 63;   // wave = head, lane = node

    // ---- graph loads from global, issued EARLY (latency hides under S+A) --
    const unsigned char* gbg = (const unsigned char*)graphi;
    const int4 il = *(const int4*)(gbg + v * MDI);               // in-list + indeg
    const unsigned ow = *(const unsigned*)(gbg + 1088 + v * MDO); // 4 KNN dsts
    const int mdin = __builtin_amdgcn_readfirstlane(((const int*)graphi)[416] & 0xFF);

    // ---- S: stage xT (coalesced global, swizzled LDS writes) ----
    for (int idx = tid; idx < 2560; idx += TPB) {
        const int vv = idx / 40, j = idx % 40;   // consecutive lanes: consecutive t
        float val = 1.0f;
        if (j < 39) {
            const int t = t0 - 15 + j;
            val = (t >= 0 && t < Tc) ? x[(b * 64 + vv) * Tc + t] : 0.f;
        }
        sm[xt_idx(j, vv >> 2, vv & 3)] = val;
    }
    __syncthreads();

    const int hs = __builtin_amdgcn_readfirstlane(h);
    const vf2* wsdh = (const vf2*)(wsdg + hs * 64);   // uniform -> s_load pairs

    // ---- Phase A: es/ed convs, {es,ed} packed accumulators ----
    float aes[8], aed[8];
    {
        const int g = v >> 2, lo = v & 3;
        const vf2 cv = *(const vf2*)(cesg + hs * 2);
        vf2 acc2[8];
        #pragma unroll
        for (int t = 0; t < 8; t++) acc2[t] = cv;
        float xr[8];
        #pragma unroll
        for (int q = 0; q < 7; q++) xr[q] = sm[xt_idx(q, g, lo)];
        #pragma unroll
        for (int k = 0; k < 32; k++) {
            xr[(k + 7) & 7] = sm[xt_idx(k + 7, g, lo)];
            const vf2 wk = wsdh[k];                  // {wes_k, wed_k} SGPR pair
            #pragma unroll
            for (int t = 0; t < 8; t++) {
                const float xv = xr[(k + t) & 7];
                acc2[t] += (vf2){xv, xv} * wk;       // v_pk_fma_f32 (splat)
            }
        }
        #pragma unroll
        for (int t = 0; t < 8; t++) {
            aes[t] = acc2[t].x * L2E;                // exp2-domain prescale
            aed[t] = acc2[t].y * L2E;
        }
    }

    // ---- Phase B: softmax via dual-scratch wide-LDS gather (6 fences) ----
    {
        float* esL0 = &sm[L_Y + h * 328];    // scratch #0 (256 floats, own head)
        float* esL1 = &sm[L_WB + h * 544];   // scratch #1 (dead until wb store)

        const int indeg = (int)(((unsigned)il.w) >> 24);
        const unsigned iw[4] = {(unsigned)il.x, (unsigned)il.y,
                                (unsigned)il.z, (unsigned)il.w};

        // self-edge term
        float den[8], Eself[8];
        #pragma unroll
        for (int t = 0; t < 8; t++) {
            Eself[t] = lexp2(aes[t] + aed[t]);
            den[t] = Eself[t];
        }

        // in-gather: BOTH t-halves staged; one drain; 2 b128 reads per edge
        *(float4*)(esL0 + v * 4) = (float4){aes[0], aes[1], aes[2], aes[3]};
        *(float4*)(esL1 + v * 4) = (float4){aes[4], aes[5], aes[6], aes[7]};
        LGKM0();
        #pragma unroll
        for (int e = 0; e < 15; e++) {
            if (e < mdin) {                  // wave-uniform bound
                const int s = (int)((iw[e >> 2] >> ((e & 3) * 8)) & 0xFF);
                const float4 ea = *(const float4*)(esL0 + s * 4);
                const float4 eb = *(const float4*)(esL1 + s * 4);
                const float valid = (e < indeg) ? 1.f : 0.f;
                den[0] += valid * lexp2(ea.x + aed[0]);
                den[1] += valid * lexp2(ea.y + aed[1]);
                den[2] += valid * lexp2(ea.z + aed[2]);
                den[3] += valid * lexp2(ea.w + aed[3]);
                den[4] += valid * lexp2(eb.x + aed[4]);
                den[5] += valid * lexp2(eb.y + aed[5]);
                den[6] += valid * lexp2(eb.z + aed[6]);
                den[7] += valid * lexp2(eb.w + aed[7]);
            }
        }
        LGKM0();

        float rden[8], wb[8];
        #pragma unroll
        for (int t = 0; t < 8; t++) {
            float r = __builtin_amdgcn_rcpf(den[t]);
            r = r * (2.f - den[t] * r);
            rden[t] = r;
            wb[t] = Eself[t] * r;
        }

        // out-gather: 2 stage-pairs (t 0..3 | t 4..7), 4 KNN edges each
        #pragma unroll
        for (int hf = 0; hf < 2; hf++) {
            const int tb4 = hf * 4;
            *(float4*)(esL0 + v * 4) = (float4){aed[tb4 + 0], aed[tb4 + 1],
                                                rden[tb4 + 0], rden[tb4 + 1]};
            *(float4*)(esL1 + v * 4) = (float4){aed[tb4 + 2], aed[tb4 + 3],
                                                rden[tb4 + 2], rden[tb4 + 3]};
            LGKM0();
            #pragma unroll
            for (int j = 0; j < 4; j++) {
                const int d = (int)((ow >> (j * 8)) & 0xFF);
                const float4 g0 = *(const float4*)(esL0 + d * 4);
                const float4 g1 = *(const float4*)(esL1 + d * 4);
                wb[tb4 + 0] = fmaf(lexp2(aes[tb4 + 0] + g0.x), g0.z, wb[tb4 + 0]);
                wb[tb4 + 1] = fmaf(lexp2(aes[tb4 + 1] + g0.y), g0.w, wb[tb4 + 1]);
                wb[tb4 + 2] = fmaf(lexp2(aes[tb4 + 2] + g1.x), g1.z, wb[tb4 + 2]);
                wb[tb4 + 3] = fmaf(lexp2(aes[tb4 + 3] + g1.y), g1.w, wb[tb4 + 3]);
            }
            LGKM0();
        }

        #pragma unroll
        for (int t = 0; t < 8; t++)
            sm[L_WB + h * 544 + t * 68 + v] = wb[t];
    }
    LGKM0();   // wave-local drain before C reads L_WB

    // ---- Phase C: y[t,c] = sum_v wb[t,v]*xT[c,v]
    //      lane = (cg 8) x (th 2) x (kq 4); permlane butterflies (VALU) ----
    {
        const int cg = v & 7;
        const int th = (v >> 3) & 1;
        const int kq = v >> 4;

        vf2 yp[4][5];
        #pragma unroll
        for (int i = 0; i < 4; i++)
            #pragma unroll
            for (int q = 0; q < 5; q++) yp[i][q] = (vf2){0.f, 0.f};

        const float* wbbase = &sm[L_WB + h * 544 + (th * 4) * 68];
        #pragma unroll
        for (int v4 = 0; v4 < 4; v4++) {
            const int vcol = kq * 16 + v4 * 4;
            float4 wrow[4];
            #pragma unroll
            for (int i = 0; i < 4; i++)
                wrow[i] = *(const float4*)(wbbase + i * 68 + vcol);
            #pragma unroll
            for (int q = 0; q < 5; q++) {
                const int row = cg * 5 + q;
                const int mg = ((kq * 4 + v4 + row) & 15) << 2;   // swizzled
                const float4 x4 = *(const float4*)(&sm[L_XT + row * 68 + mg]);
                const vf2 x01 = (vf2){x4.x, x4.y}, x23 = (vf2){x4.z, x4.w};
                #pragma unroll
                for (int i = 0; i < 4; i++) {
                    const vf2 w01 = (vf2){wrow[i].x, wrow[i].y};
                    const vf2 w23 = (vf2){wrow[i].z, wrow[i].w};
                    yp[i][q] += w01 * x01;          // v_pk_fma_f32
                    yp[i][q] += w23 * x23;
                }
            }
        }
        float ya[4][5];
        #pragma unroll
        for (int i = 0; i < 4; i++)
            #pragma unroll
            for (int q = 0; q < 5; q++) {
                float s = yp[i][q].x + yp[i][q].y;
                ya[i][q] = bfly32_sum(bfly16_sum(s));
            }
        float* yw = &sm[L_Y + h * 328 + (th * 4 + kq) * 41 + cg * 5];
        #pragma unroll
        for (int q = 0; q < 5; q++) {
            float a01 = (kq & 1) ? ya[1][q] : ya[0][q];
            float a23 = (kq & 1) ? ya[3][q] : ya[2][q];
            yw[q] = (kq & 2) ? a23 : a01;
        }
    }
    LGKM0();

    // ---- Phase D+E fused (wave-local): g -> bn2+elu -> pool8 ----
    {
        const int t = v >> 3, o = v & 7;
        const int f2d = h * 8 + o;
        const float4* wf4 = (const float4*)(wfTp + f2d * 32);

        const float* yr = &sm[L_Y + h * 328 + t * 41];
        float acc = 0.f;                     // chl folded into c2 (rowsum==64)
        #pragma unroll
        for (int k4 = 0; k4 < 8; k4++) {
            const float4 w = wf4[k4];
            acc = fmaf(w.x, yr[t + 4 * k4 + 0],
                  fmaf(w.y, yr[t + 4 * k4 + 1],
                  fmaf(w.z, yr[t + 4 * k4 + 2],
                  fmaf(w.w, yr[t + 4 * k4 + 3], acc))));
        }

        const float a2 = a2c2[f2d], c2 = a2c2[32 + f2d];
        float y = fmaf(a2, acc * (1.f / 64.f), c2);
        y = y > 0.f ? y : __expf(y) - 1.f;
        y += __shfl_xor(y, 8);
        y = bfly32_sum(bfly16_sum(y));
        if (v < 8)
            pout[(b * T2c + tile) * 32 + h * 8 + v] = y * 0.125f;
    }
}

// ---------------------------------------------------------------------------
// conv3(K=16,'same') + bn3 + elu + avgpool(4): p[B,192,32] -> out[B,32,48].
// ---------------------------------------------------------------------------
__global__ __launch_bounds__(TPB) void conv3_kernel(const float* __restrict__ pp,
                                                    const float* __restrict__ w3,
                                                    const float* __restrict__ g3,
                                                    const float* __restrict__ b3,
                                                    const float* __restrict__ m3,
                                                    const float* __restrict__ v3,
                                                    float* __restrict__ outp)
{
    __shared__ float pl[63 * 32];
    __shared__ float q[48 * 32];
    const int tid = threadIdx.x;
    const int b = blockIdx.x >> 2, cc = blockIdx.x & 3;

    for (int idx = tid; idx < 63 * 32; idx += TPB) {
        int r = idx >> 5, f2 = idx & 31;
        int tog = cc * 48 - 7 + r;
        pl[idx] = (tog >= 0 && tog < T2c) ? pp[(b * T2c + tog) * 32 + f2] : 0.f;
    }
    __syncthreads();

    const int f2o = tid & 31, grp = tid >> 5;
    const int tb = grp * 6;
    float acc[6] = { 0.f, 0.f, 0.f, 0.f, 0.f, 0.f };
    for (int f2i = 0; f2i < 32; f2i++) {
        float seg[21];
        #pragma unroll
        for (int r = 0; r < 21; r++) seg[r] = pl[(tb + r) * 32 + f2i];
        const float4* wrow = (const float4*)(w3 + (f2o * 32 + f2i) * 16);
        #pragma unroll
        for (int k4 = 0; k4 < 4; k4++) {
            const float4 w4 = wrow[k4];
            #pragma unroll
            for (int j = 0; j < 6; j++) {
                acc[j] = fmaf(seg[j + k4 * 4 + 0], w4.x,
                         fmaf(seg[j + k4 * 4 + 1], w4.y,
                         fmaf(seg[j + k4 * 4 + 2], w4.z,
                         fmaf(seg[j + k4 * 4 + 3], w4.w, acc[j]))));
            }
        }
    }
    const float a3 = g3[f2o] * rsqrtf(v3[f2o] + EPSc);
    const float c3 = b3[f2o] - a3 * m3[f2o];
    #pragma unroll
    for (int j = 0; j < 6; j++) {
        float y = fmaf(a3, acc[j], c3);
        y = y > 0.f ? y : __expf(y) - 1.f;
        q[(tb + j) * 32 + f2o] = y;
    }
    __syncthreads();
    for (int idx = tid; idx < 12 * 32; idx += TPB) {
        int t4 = idx >> 5, f2 = idx & 31;
        int r0 = t4 * 4;
        float s = q[r0 * 32 + f2] + q[(r0 + 1) * 32 + f2] +
                  q[(r0 + 2) * 32 + f2] + q[(r0 + 3) * 32 + f2];
        outp[(b * 32 + f2) * 48 + cc * 12 + t4] = s * 0.25f;
    }
}

// ---------------------------------------------------------------------------
extern "C" void kernel_launch(void* const* d_in, const int* in_sizes, int n_in,
                              void* d_out, int out_size, void* d_ws, size_t ws_size,
                              hipStream_t stream)
{
    const float* x    = (const float*)d_in[0];
    const float* c1w  = (const float*)d_in[1];
    const float* g1   = (const float*)d_in[2];
    const float* b1   = (const float*)d_in[3];
    const float* m1   = (const float*)d_in[4];
    const float* v1   = (const float*)d_in[5];
    const float* W    = (const float*)d_in[6];
    const float* asrc = (const float*)d_in[7];
    const float* adst = (const float*)d_in[8];
    const float* bias = (const float*)d_in[9];
    const float* g2   = (const float*)d_in[10];
    const float* b2   = (const float*)d_in[11];
    const float* m2   = (const float*)d_in[12];
    const float* v2   = (const float*)d_in[13];
    const float* w3   = (const float*)d_in[14];
    const float* g3   = (const float*)d_in[15];
    const float* b3   = (const float*)d_in[16];
    const float* m3   = (const float*)d_in[17];
    const float* v3   = (const float*)d_in[18];
    const int*   ei   = (const int*)d_in[19];
    const int    ne   = in_sizes[19] / 2;

    float* ws = (float*)d_ws;

    prep_kernel<<<1, TPB, 0, stream>>>(c1w, g1, b1, m1, v1, W, asrc, adst,
                                       bias, g2, b2, m2, v2, ei, ne, ws);

    gat_kernel<<<Bc * T2c, TPB, 0, stream>>>(x,
                                             ws + OW_WFT,
                                             ws + OW_CES,
                                             ws + OW_WSD,
                                             ws + OW_A2C2,
                                             (const int*)(ws + OW_GRAPH),
                                             ws + OW_P);

    conv3_kernel<<<Bc * 4, TPB, 0, stream>>>(ws + OW_P, w3, g3, b3, m3, v3,
                                             (float*)d_out);
}